// Round 15
// baseline (151.772 us; speedup 1.0000x reference)
//
#include <hip/hip_runtime.h>
#include <math.h>

#define N_POSE   1024
#define M_TRAIN  10000
#define NJOINT   21
#define KNEIGH   5
#define CLIPV    (1.0f - 1e-7f)
#define HPI_F    1.57079632679490f
#define BIGF     1e30f
#define TPB      256
#define MB       10                       // m-values per register block
#define QT_FLOATS (N_POSE * NJOINT * 4)   // transposed normalized q in ws

// prepass: normalize query quats AND transpose to [j][n] so the hot loop's
// q-load is coalesced (lane n -> qT + (j*1024+n)*16B, 1024B/instr).
__global__ __launch_bounds__(256)
void pose_norm_t_kernel(const float* __restrict__ pose, float* __restrict__ qT) {
    int i = blockIdx.x * blockDim.x + threadIdx.x;   // i = n*21 + j
    if (i >= N_POSE * NJOINT) return;
    int n = i / NJOINT, j = i % NJOINT;
    float4 v = ((const float4*)pose)[i];
    float inv = rsqrtf(v.x * v.x + v.y * v.y + v.z * v.z + v.w * v.w);
    v.x *= inv; v.y *= inv; v.z *= inv; v.w *= inv;
    ((float4*)qT)[(size_t)j * N_POSE + n] = v;
}

// R13's clean dataflow (j-outer/m-inner register block, coalesced qT loads,
// blockIdx-only train indexing -> s_load/SGPR) with the two measured gaps
// closed: (1) chunks=1000 -> 4000 blocks = 62 waves/CU requested (R13 was
// 31% occupancy on a 1000-block grid; R9 proved 78% at 4000 blocks);
// (2) j fully unrolled so the 210 s_loads pipeline across j with partial
// lgkmcnt waits instead of a full drain per j.
__global__ __launch_bounds__(TPB)
void pose_dist_kernel(const float* __restrict__ qT,
                      const float* __restrict__ train,
                      float* __restrict__ topk,
                      int chunks, int mchunk) {
    const int nb = blockIdx.x / chunks;   // row-group (0..3)
    const int cb = blockIdx.x % chunks;   // m-chunk
    const int n  = nb * TPB + threadIdx.x;

    const char* tb = (const char*)train + (size_t)cb * mchunk * 336;
    const float4* __restrict__ qbase = (const float4*)qT + n;   // + j*1024 per j

    float t0 = BIGF, t1 = BIGF, t2 = BIGF, t3 = BIGF, t4 = BIGF;

#pragma unroll 1
    for (int mb = 0; mb < mchunk; mb += MB) {
        const char* tmb = tb + (size_t)mb * 336;
        float acc[MB];
#pragma unroll
        for (int mm = 0; mm < MB; ++mm) acc[mm] = 0.f;

#pragma unroll
        for (int j = 0; j < NJOINT; ++j) {
            float4 qc = qbase[(size_t)j * N_POSE];  // coalesced, 1 instr
#pragma unroll
            for (int mm = 0; mm < MB; ++mm) {
                float4 u = *(const float4*)(tmb + mm * 336 + j * 16); // s_load
                float d = u.x * qc.x + u.y * qc.y + u.z * qc.z + u.w * qc.w;
                float a = fminf(fabsf(d), CLIPV);
                float pl = fmaf(a, -0.0187293f, 0.0742610f);
                pl = fmaf(a, pl, -0.2121144f);
                pl = fmaf(a, pl, 1.5707288f);
                float r  = __builtin_amdgcn_sqrtf(1.0f - a) * pl;
                acc[mm] += __builtin_copysignf(HPI_F - r, d);
            }
        }

#pragma unroll
        for (int mm = 0; mm < MB; ++mm) {
            float v = (NJOINT * HPI_F - acc[mm]) * 0.5f;
            t4 = fminf(t4, fmaxf(t3, v));
            t3 = fminf(t3, fmaxf(t2, v));
            t2 = fminf(t2, fmaxf(t1, v));
            t1 = fminf(t1, fmaxf(t0, v));
            t0 = fminf(t0, v);
        }
    }

    // [cb][n][k]: adjacent rows write adjacent 20B -> coalesced stores
    float* w = topk + ((size_t)cb * N_POSE + n) * KNEIGH;
    w[0] = t0; w[1] = t1; w[2] = t2; w[3] = t3; w[4] = t4;
}

// one wave per query row: merge chunks*5 candidates -> mean of top-5
__global__ __launch_bounds__(64)
void pose_reduce_kernel(const float* __restrict__ topk, float* __restrict__ out,
                        int chunks) {
    const int n = blockIdx.x;
    const int lane = threadIdx.x;
    const int total = chunks * KNEIGH;

    float t0 = BIGF, t1 = BIGF, t2 = BIGF, t3 = BIGF, t4 = BIGF;
    for (int i = lane; i < total; i += 64) {
        int cb = i / KNEIGH, k = i % KNEIGH;
        float v = topk[((size_t)cb * N_POSE + n) * KNEIGH + k];
        t4 = fminf(t4, fmaxf(t3, v));
        t3 = fminf(t3, fmaxf(t2, v));
        t2 = fminf(t2, fmaxf(t1, v));
        t1 = fminf(t1, fmaxf(t0, v));
        t0 = fminf(t0, v);
    }

    float sum = 0.f;
#pragma unroll
    for (int r = 0; r < KNEIGH; ++r) {
        float v = t0; int who = lane;
        for (int off = 32; off; off >>= 1) {
            float ov = __shfl_xor(v, off);
            int   ow = __shfl_xor(who, off);
            if (ov < v || (ov == v && ow < who)) { v = ov; who = ow; }
        }
        sum += v;
        if (lane == who) { t0 = t1; t1 = t2; t2 = t3; t3 = t4; t4 = BIGF; }
    }
    if (lane == 0) out[n] = sum * (1.0f / KNEIGH);
}

extern "C" void kernel_launch(void* const* d_in, const int* in_sizes, int n_in,
                              void* d_out, int out_size, void* d_ws, size_t ws_size,
                              hipStream_t stream) {
    const float* pose  = (const float*)d_in[0];
    const float* train = (const float*)d_in[1];
    float* out  = (float*)d_out;
    float* qT   = (float*)d_ws;                 // QT_FLOATS floats
    float* topk = (float*)d_ws + QT_FLOATS;

    // tiers divide 10000 and keep mchunk % 10 == 0
    size_t base = (size_t)QT_FLOATS * sizeof(float);
    int chunks = 1000;
    if (base + (size_t)N_POSE * chunks * KNEIGH * sizeof(float) > ws_size) chunks = 500;
    if (base + (size_t)N_POSE * chunks * KNEIGH * sizeof(float) > ws_size) chunks = 250;
    if (base + (size_t)N_POSE * chunks * KNEIGH * sizeof(float) > ws_size) chunks = 125;
    const int mchunk = M_TRAIN / chunks;

    pose_norm_t_kernel<<<dim3((N_POSE * NJOINT + 255) / 256), dim3(256), 0, stream>>>(pose, qT);

    dim3 grid1((N_POSE / TPB) * chunks);   // 4 row-groups x 1000 chunks = 4000 blocks
    pose_dist_kernel<<<grid1, dim3(TPB), 0, stream>>>(qT, train, topk, chunks, mchunk);

    pose_reduce_kernel<<<dim3(N_POSE), dim3(64), 0, stream>>>(topk, out, chunks);
}